// Round 13
// baseline (285.499 us; speedup 1.0000x reference)
//
#include <hip/hip_runtime.h>

#define B    128
#define D_IN 256
#define H    256

#define BH      (B * H)            // 32768
#define BIG     (B * D_IN * H)     // 8388608
#define OFF_H1   0
#define OFF_H2   (1 * BH)
#define OFF_NGM0 (2 * BH)
#define OFF_NGM1 (3 * BH)
#define OFF_NGM2 (4 * BH)
#define OFF_NGM3 (5 * BH)
#define OFF_NGM4 (6 * BH)
#define OFF_NGM5 (OFF_NGM4 + 1 * BIG)
#define OFF_NGM6 (OFF_NGM4 + 2 * BIG)
#define OFF_NGM7 (OFF_NGM4 + 3 * BIG)

// ---------------------------------------------------------------------------
// Kernel 1: per-(b,h) small work.
//   - w1x = x_t @ wx1, w2x = x_t @ wx2  (x row staged in LDS, coalesced wx reads)
//   - c1/c2, relu outputs, d1/d2, ngm0..ngm3
//   - stash 6 coefficient arrays (d1*g, d1*phi, d1*norm, d2*g, d2*phi, d2*norm)
//     into d_ws for the big elementwise kernel.
// grid = B blocks, H threads.
// ---------------------------------------------------------------------------
__global__ __launch_bounds__(H) void k_small(
    const float* __restrict__ x,   const float* __restrict__ hc1, const float* __restrict__ hc2,
    const float* __restrict__ gm0, const float* __restrict__ gm1,
    const float* __restrict__ gm2, const float* __restrict__ gm3,
    const float* __restrict__ rp,  const float* __restrict__ thp,
    const float* __restrict__ wx1, const float* __restrict__ wx2,
    float* __restrict__ out, float* __restrict__ ws)
{
    const int b = blockIdx.x;
    const int h = threadIdx.x;

    __shared__ float xs[D_IN];
    xs[h] = x[b * D_IN + h];
    __syncthreads();

    // per-h gate scalars
    const float er  = expf(rp[h]);
    const float r   = expf(-er);
    const float th  = expf(thp[h]);
    const float g   = r * cosf(th);
    const float phi = r * sinf(th);
    const float nrm = sqrtf(1.0f - r * r);

    // w1x / w2x dot products (K = D_IN), coalesced over h
    float acc1 = 0.0f, acc2 = 0.0f;
#pragma unroll 8
    for (int k = 0; k < D_IN; ++k) {
        const float xv = xs[k];
        acc1 = fmaf(xv, wx1[k * H + h], acc1);
        acc2 = fmaf(xv, wx2[k * H + h], acc2);
    }

    const int idx = b * H + h;
    const float h1 = hc1[idx], h2 = hc2[idx];

    const float c1 = g * h1 - phi * h2 + nrm * acc1;
    const float c2 = g * h2 + phi * h1 + nrm * acc2;
    const float d1 = (c1 > 0.0f) ? 1.0f : 0.0f;
    const float d2 = (c2 > 0.0f) ? 1.0f : 0.0f;

    out[OFF_H1 + idx] = fmaxf(c1, 0.0f);
    out[OFF_H2 + idx] = fmaxf(c2, 0.0f);

    const float m0 = gm0[idx], m1 = gm1[idx], m2 = gm2[idx], m3 = gm3[idx];

    const float dgr = -er * g;           // d_g_w_r
    const float dpr = -er * phi;         // d_phi_w_r
    const float dgt = -th * phi;         // d_g_w_th
    const float dpt =  th * g;           // d_phi_w_th
    const float dnr =  er * r * r / nrm; // d_norm_w_r

    out[OFF_NGM0 + idx] = d1 * (dgr * h1 + g * m0 - dpr * h2 - phi * m1 + dnr * acc1);
    out[OFF_NGM1 + idx] = d2 * (dgr * h2 + g * m1 + dpr * h1 + phi * m0 + dnr * acc2);
    out[OFF_NGM2 + idx] = d1 * (dgt * h1 + g * m2 - dpt * h2 - phi * m3);
    out[OFF_NGM3 + idx] = d2 * (dgt * h2 + g * m3 + dpt * h1 + phi * m2);

    // coefficients for the big kernel (6 arrays of B*H f32 in ws)
    ws[0 * BH + idx] = d1 * g;
    ws[1 * BH + idx] = d1 * phi;
    ws[2 * BH + idx] = d1 * nrm;
    ws[3 * BH + idx] = d2 * g;
    ws[4 * BH + idx] = d2 * phi;
    ws[5 * BH + idx] = d2 * nrm;
}

// ---------------------------------------------------------------------------
// Kernel 2: ngm4..ngm7 — pure elementwise over (B, D_IN, H), float4-vectorized.
//   Thread t owns fixed (b, h4) and 4 consecutive j values:
//     b = t>>12, jg = (t>>6)&63, h4 = t&63  → j = jg*4+jj
//   Coefficients (6 float4) loaded ONCE into registers, reused across 4 j.
//   Lane = h4 → gm loads/stores fully coalesced; x[b,j] wave-uniform.
//   524288 threads = 2048 blocks × 256 — 8 blocks/CU, fully resident.
// ---------------------------------------------------------------------------
__global__ __launch_bounds__(256) void k_big(
    const float4* __restrict__ gm4, const float4* __restrict__ gm5,
    const float4* __restrict__ gm6, const float4* __restrict__ gm7,
    const float*  __restrict__ x,
    const float4* __restrict__ wsq,
    float4* __restrict__ o4, float4* __restrict__ o5,
    float4* __restrict__ o6, float4* __restrict__ o7)
{
    const int t  = blockIdx.x * 256 + threadIdx.x;   // 0 .. 524287
    const int b  = t >> 12;                          // / 4096
    const int jg = (t >> 6) & 63;
    const int h4 = t & 63;

    const int CQ = BH / 4;                           // 8192 quads per coeff array
    const int ci = (b << 6) + h4;

    const float4 A1 = wsq[0 * CQ + ci];
    const float4 B1 = wsq[1 * CQ + ci];
    const float4 N1 = wsq[2 * CQ + ci];
    const float4 A2 = wsq[3 * CQ + ci];
    const float4 B2 = wsq[4 * CQ + ci];
    const float4 N2 = wsq[5 * CQ + ci];

    const int base_j = jg << 2;

#pragma unroll
    for (int jj = 0; jj < 4; ++jj) {
        const int j = base_j + jj;
        const int i = (b << 14) + (j << 6) + h4;     // quad index into big arrays

        const float xv = x[(b << 8) + j];

        const float4 g4 = gm4[i], g5 = gm5[i], g6 = gm6[i], g7 = gm7[i];

        float4 r4, r5, r6, r7;
#define COMP(c)                                                       \
        r4.c = fmaf(N1.c, xv, fmaf(A1.c, g4.c, -(B1.c * g5.c)));      \
        r5.c = fmaf(A2.c, g5.c, B2.c * g4.c);                         \
        r6.c = fmaf(A1.c, g6.c, -(B1.c * g7.c));                      \
        r7.c = fmaf(N2.c, xv, fmaf(A2.c, g7.c, B2.c * g6.c));
        COMP(x) COMP(y) COMP(z) COMP(w)
#undef COMP

        o4[i] = r4;
        o5[i] = r5;
        o6[i] = r6;
        o7[i] = r7;
    }
}

extern "C" void kernel_launch(void* const* d_in, const int* in_sizes, int n_in,
                              void* d_out, int out_size, void* d_ws, size_t ws_size,
                              hipStream_t stream) {
    const float* x_t  = (const float*)d_in[0];
    const float* hc1  = (const float*)d_in[1];
    const float* hc2  = (const float*)d_in[2];
    const float* gm0  = (const float*)d_in[3];
    const float* gm1  = (const float*)d_in[4];
    const float* gm2  = (const float*)d_in[5];
    const float* gm3  = (const float*)d_in[6];
    const float* gm4  = (const float*)d_in[7];
    const float* gm5  = (const float*)d_in[8];
    const float* gm6  = (const float*)d_in[9];
    const float* gm7  = (const float*)d_in[10];
    const float* rp   = (const float*)d_in[11];
    const float* thp  = (const float*)d_in[12];
    const float* wx1  = (const float*)d_in[13];
    const float* wx2  = (const float*)d_in[14];

    float* out = (float*)d_out;
    float* ws  = (float*)d_ws;

    k_small<<<B, H, 0, stream>>>(x_t, hc1, hc2, gm0, gm1, gm2, gm3,
                                 rp, thp, wx1, wx2, out, ws);

    const int threads_total = B * 64 * 64;           // 524288
    k_big<<<threads_total / 256, 256, 0, stream>>>(
        (const float4*)gm4, (const float4*)gm5, (const float4*)gm6, (const float4*)gm7,
        x_t, (const float4*)ws,
        (float4*)(out + OFF_NGM4), (float4*)(out + OFF_NGM5),
        (float4*)(out + OFF_NGM6), (float4*)(out + OFF_NGM7));
}